// Round 2
// baseline (154.937 us; speedup 1.0000x reference)
//
#include <hip/hip_runtime.h>
#include <math.h>

// RoI max pooling: feats (1,256,128,128) f32, rois (1,256,4) int32 {x,y,w,h},
// out (N=256, C=256, 7, 7) f32.
// One wave per (n, c): lane = column offset inside the roi (w <= 56 < 64).
// Per row-bin: coalesced row loads + fmax chain -> per-lane rowmax;
// column-bin reduce via 8 masked __shfl gathers (ref caps bins at MAX_BIN=8).
// NOTE: reference clamps BOTH row and column bin extent to 8 (dr/dc in
// range(8)) -- row loop must be r in [sy, min(ey, sy+8)).
// Grid order n-fastest so 256 consecutive blocks share 4 channel planes (L2).

constexpr int kC = 256, kH = 128, kW = 128, kN = 256, kOut = 7;

__global__ __launch_bounds__(256) void roipool_kernel(
    const float* __restrict__ feats,
    const int* __restrict__ rois,
    float* __restrict__ out) {
  const int lane = threadIdx.x & 63;
  const int wave = threadIdx.x >> 6;
  const int bid  = blockIdx.x;
  const int n  = bid & (kN - 1);
  const int cg = bid >> 8;            // 0..63
  const int c  = (cg << 2) | wave;    // 4 channels per block

  const int4 roi = ((const int4*)rois)[n];
  // force wave-uniform -> scalar loop bounds, no exec-mask loops
  const int x = __builtin_amdgcn_readfirstlane(roi.x);
  const int y = __builtin_amdgcn_readfirstlane(roi.y);
  const int w = __builtin_amdgcn_readfirstlane(roi.z);
  const int h = __builtin_amdgcn_readfirstlane(roi.w);

  const float* __restrict__ plane = feats + (size_t)c * (kH * kW);

  // per-lane column-bin bounds (relative to x); only lanes < 7 meaningful
  const int j   = (lane < kOut) ? lane : 0;
  const int sxr = (j * w) / kOut;
  const int exr = ((j + 1) * w + kOut - 1) / kOut;

  float o[kOut];

#pragma unroll
  for (int i = 0; i < kOut; ++i) {
    const int sy = y + (i * h) / kOut;
    int ey = y + ((i + 1) * h + kOut - 1) / kOut;
    if (ey > sy + 8) ey = sy + 8;     // MAX_BIN=8 clamp (matches reference)
    float m = -INFINITY;
    if (lane < w) {  // exec-masked: no OOB loads for lanes >= w
      const float* p = plane + sy * kW + x + lane;
      for (int r = sy; r < ey; ++r) {   // uniform bounds, <= 8 iters
        m = fmaxf(m, *p);
        p += kW;
      }
    }
    // column-bin max: gather up to 8 lanes [sxr, min(exr, sxr+8))
    float oi = -INFINITY;
#pragma unroll
    for (int t = 0; t < 8; ++t) {
      const int k = sxr + t;
      const float v = __shfl(m, k & 63, 64);
      if (k < exr) oi = fmaxf(oi, v);
    }
    o[i] = oi;
  }

  // transpose 7x7 results to lanes 0..48 -> one coalesced 196B store
  float sv = 0.f;
#pragma unroll
  for (int i = 0; i < kOut; ++i) {
    const float v = __shfl(o[i], (lane - i * kOut) & 63, 64);
    if ((unsigned)(lane - i * kOut) < (unsigned)kOut) sv = v;
  }
  if (lane < kOut * kOut)
    out[((size_t)n * kC + c) * (kOut * kOut) + lane] = sv;
}

extern "C" void kernel_launch(void* const* d_in, const int* in_sizes, int n_in,
                              void* d_out, int out_size, void* d_ws, size_t ws_size,
                              hipStream_t stream) {
  const float* feats = (const float*)d_in[0];
  const int*   rois  = (const int*)d_in[1];
  float*       out   = (float*)d_out;
  dim3 grid((kC / 4) * kN);   // cg-major, n-fastest: bid = cg*256 + n
  dim3 block(256);
  roipool_kernel<<<grid, block, 0, stream>>>(feats, rois, out);
}

// Round 3
// 60.527 us; speedup vs baseline: 2.5598x; 2.5598x over previous
//
#include <hip/hip_runtime.h>
#include <math.h>

// RoI max pooling: feats (1,256,128,128) f32, rois (1,256,4) int32 {x,y,w,h},
// out (N=256, C=256, 7, 7) f32.
// One wave per (n, c): lane = column offset inside the roi (w <= 56 < 64).
// Per row-bin: 8 UNROLLED independent row loads (matches reference dr in
// range(MAX_BIN=8), row index clamped, masked by sy+dr<ey) -> fmax tree.
// Column-bin reduce via 8 masked __shfl gathers (dc in range(8)).
// Column clamped to min(lane, w-1): all 64 lanes load valid addrs; lanes >= w
// produce dead duplicates that are never gathered (gather k < exr <= w).
// XCD-affine mapping: cg & 7 == bid & 7, n-fastest per cg -> each 4-plane
// group (256 KB) swept by 256 consecutive blocks on ONE XCD's L2.

constexpr int kC = 256, kH = 128, kW = 128, kN = 256, kOut = 7;

__global__ __launch_bounds__(256) void roipool_kernel(
    const float* __restrict__ feats,
    const int* __restrict__ rois,
    float* __restrict__ out) {
  const int lane = threadIdx.x & 63;
  const int wave = threadIdx.x >> 6;
  const int bid  = blockIdx.x;

  // XCD-affine: xcd = bid & 7 (round-robin dispatch heuristic; perf only)
  const int xcd = bid & 7;
  const int idx = bid >> 3;             // 0..2047
  const int n   = idx & (kN - 1);       // n-fastest on each XCD
  const int cg  = ((idx >> 8) << 3) | xcd;  // 0..63, cg&7 == xcd
  const int c   = (cg << 2) | wave;

  const int4 roi = ((const int4*)rois)[n];
  const int x = __builtin_amdgcn_readfirstlane(roi.x);
  const int y = __builtin_amdgcn_readfirstlane(roi.y);
  const int w = __builtin_amdgcn_readfirstlane(roi.z);
  const int h = __builtin_amdgcn_readfirstlane(roi.w);

  const float* __restrict__ plane = feats + (size_t)c * (kH * kW);

  // all lanes get a valid column (duplicates for lane >= w, never consumed)
  const int col = x + ((lane < w) ? lane : (w - 1));
  const float* __restrict__ pcol = plane + col;

  // per-lane column-bin bounds (relative to x); only lanes < 7 meaningful
  const int j   = (lane < kOut) ? lane : 6;
  const int sxr = (j * w) / kOut;
  int exr = ((j + 1) * w + kOut - 1) / kOut;
  if (exr > sxr + 8) exr = sxr + 8;     // MAX_BIN clamp (columns)

  float o[kOut];

#pragma unroll
  for (int i = 0; i < kOut; ++i) {
    const int sy = y + (i * h) / kOut;
    int ey = y + ((i + 1) * h + kOut - 1) / kOut;
    if (ey > sy + 8) ey = sy + 8;       // MAX_BIN clamp (rows)
    const int nr = ey - sy;             // 1..8, wave-uniform

    // 8 independent clamped row loads (reference: ridx=clip(sy+dr,0,H-1))
    float v[8];
#pragma unroll
    for (int dr = 0; dr < 8; ++dr) {
      int r = sy + dr;
      if (r > kH - 1) r = kH - 1;
      v[dr] = pcol[r * kW];
    }
    // masked max tree (mask wave-uniform: dr < nr)
    float m = -INFINITY;
#pragma unroll
    for (int dr = 0; dr < 8; ++dr)
      m = fmaxf(m, (dr < nr) ? v[dr] : -INFINITY);

    // column-bin max: gather lanes [sxr, exr), width <= 8
    float oi = -INFINITY;
#pragma unroll
    for (int t = 0; t < 8; ++t) {
      const int k = sxr + t;
      const float vv = __shfl(m, k & 63, 64);
      if (k < exr) oi = fmaxf(oi, vv);
    }
    o[i] = oi;
  }

  // transpose 7x7 results to lanes 0..48 -> one coalesced 196B store
  float sv = 0.f;
#pragma unroll
  for (int i = 0; i < kOut; ++i) {
    const float vv = __shfl(o[i], (lane - i * kOut) & 63, 64);
    if ((unsigned)(lane - i * kOut) < (unsigned)kOut) sv = vv;
  }
  if (lane < kOut * kOut)
    out[((size_t)n * kC + c) * (kOut * kOut) + lane] = sv;
}

extern "C" void kernel_launch(void* const* d_in, const int* in_sizes, int n_in,
                              void* d_out, int out_size, void* d_ws, size_t ws_size,
                              hipStream_t stream) {
  const float* feats = (const float*)d_in[0];
  const int*   rois  = (const int*)d_in[1];
  float*       out   = (float*)d_out;
  dim3 grid((kC / 4) * kN);
  dim3 block(256);
  roipool_kernel<<<grid, block, 0, stream>>>(feats, rois, out);
}

// Round 4
// 49.712 us; speedup vs baseline: 3.1167x; 1.2175x over previous
//
#include <hip/hip_runtime.h>
#include <math.h>

// RoI max pooling: feats (1,256,128,128) f32, rois (1,256,4) int32 {x,y,w,h},
// out (N=256, C=256, 7, 7) f32.  One wave per (n, c); lane = roi column.
//
// Load phase (exec-masked lane < w): per row-bin, 8 batched independent loads
// with DUP-ROW clamp r = sy + (dr < nr ? dr : 0)  -- same index set as the
// reference's masked dr in range(8), but needs no cndmask tree and keeps all
// row math on the scalar pipe (sy, ey wave-uniform). Dup loads re-hit the
// just-fetched row sy line (L1), so no extra L2 traffic.
// Rowmax -> lds[bin][72] (conflict-free, stride 72 dwords).
//
// Read phase (all lanes): lane l = i*7+j reads lds[i][sxr_j .. sxr_j+7]
// via immediate-offset ds_reads, masks t < wj (MAX_BIN=8 clamp), 7 maxes.
// Lane l IS the output offset i*7+j -> no transpose, one contiguous store.
// Same-wave DS ordering is in-order; lgkmcnt(0) fence, no barrier needed.

constexpr int kC = 256, kH = 128, kW = 128, kN = 256, kOut = 7;
constexpr int kStr = 72;  // dwords per bin row in LDS (72 & 31 == 8: low conflict)

__global__ __launch_bounds__(256) void roipool_kernel(
    const float* __restrict__ feats,
    const int* __restrict__ rois,
    float* __restrict__ out) {
  __shared__ float lds[4 * kOut * kStr];  // 4 waves * 2016B = 8064B

  const int lane = threadIdx.x & 63;
  // readfirstlane -> wave id provably uniform -> c uniform -> scalar addressing
  const int wid  = __builtin_amdgcn_readfirstlane(threadIdx.x) >> 6;
  const int bid  = blockIdx.x;

  // XCD-affine: xcd = bid & 7, n-fastest per cg (perf heuristic only)
  const int xcd = bid & 7;
  const int idx = bid >> 3;
  const int n   = idx & (kN - 1);
  const int cg  = ((idx >> 8) << 3) | xcd;
  const int c   = (cg << 2) | wid;

  const int4 roi = ((const int4*)rois)[n];
  const int x = __builtin_amdgcn_readfirstlane(roi.x);
  const int y = __builtin_amdgcn_readfirstlane(roi.y);
  const int w = __builtin_amdgcn_readfirstlane(roi.z);
  const int h = __builtin_amdgcn_readfirstlane(roi.w);

  float* __restrict__ wlds = lds + wid * (kOut * kStr);

  // ---- load phase: lanes < w only (no traffic from dead lanes) ----
  if (lane < w) {
    const float* __restrict__ pcol = feats + (size_t)c * (kH * kW) + x + lane;
#pragma unroll
    for (int i = 0; i < kOut; ++i) {
      const int sy = y + (i * h) / kOut;
      int ey = y + ((i + 1) * h + kOut - 1) / kOut;
      int nr = ey - sy;
      if (nr > 8) nr = 8;  // MAX_BIN clamp
      float v[8];
#pragma unroll
      for (int dr = 0; dr < 8; ++dr) {
        const int r = sy + ((dr < nr) ? dr : 0);  // dup-row clamp (uniform)
        v[dr] = pcol[(size_t)r * kW];
      }
      float m = v[0];
#pragma unroll
      for (int dr = 1; dr < 8; ++dr) m = fmaxf(m, v[dr]);
      wlds[i * kStr + lane] = m;
    }
  }

  // same-wave DS in-order; drain writes before dependent cross-lane reads
  asm volatile("s_waitcnt lgkmcnt(0)" ::: "memory");

  // ---- read phase: lane l = i*7 + j -> output offset directly ----
  const int l49 = (lane < 49) ? lane : 48;
  const int i   = (l49 * 37) >> 8;        // floor(l49/7), exact for 0..48
  const int j   = l49 - i * 7;
  const int jw  = j * w;
  const int sxr = (jw * 9363) >> 16;                    // floor(jw/7)
  const int exr = ((jw + w + 6) * 9363) >> 16;          // floor(((j+1)w+6)/7)
  int wj = exr - sxr;
  if (wj > 8) wj = 8;                                   // MAX_BIN clamp

  const float* __restrict__ rbase = wlds + i * kStr + sxr;
  float acc = rbase[0];                                 // t=0 always valid
#pragma unroll
  for (int t = 1; t < 8; ++t) {
    const float v = rbase[t];                 // imm-offset ds_read; junk ok,
    acc = fmaxf(acc, (t < wj) ? v : -INFINITY);  // cndmask discards (even NaN)
  }

  if (lane < 49)
    out[((size_t)n * kC + c) * 49 + lane] = acc;
}

extern "C" void kernel_launch(void* const* d_in, const int* in_sizes, int n_in,
                              void* d_out, int out_size, void* d_ws, size_t ws_size,
                              hipStream_t stream) {
  const float* feats = (const float*)d_in[0];
  const int*   rois  = (const int*)d_in[1];
  float*       out   = (float*)d_out;
  dim3 grid((kC / 4) * kN);
  dim3 block(256);
  roipool_kernel<<<grid, block, 0, stream>>>(feats, rois, out);
}

// Round 5
// 37.736 us; speedup vs baseline: 4.1058x; 1.3174x over previous
//
#include <hip/hip_runtime.h>
#include <math.h>

// RoI max pooling: feats (1,256,128,128) f32, rois (1,256,4) int32 {x,y,w,h},
// out (N=256, C=256, 7, 7) f32.  One wave per (n, c).
//
// Load phase (float4-vectorized): lanes = 16 col-quads (q=lane&15, covers the
// 16B-aligned window xa..xa+4*qmax+3 ⊇ [x, x+w)) × {row-slot = bit4} ×
// {bin = bit5}. Two bins per pass-group; 4 passes load rows idx=2p+slot with
// dup-clamp idx->min(idx, nr-1) (same operand set as reference's masked
// dr in range(MAX_BIN=8)). Wave-uniform skip when 2p >= max(nr0,nr1).
// Row-slot combine: ds_swizzle xor-16 (lane pairs share q -> same exec mask).
// One ds_write_b128 per bin (contiguous, conflict-free). kStr=68 dwords:
// 16B-aligned rows, bank base 4i (i=0..6 distinct mod 32).
//
// Read phase: lane l=i*7+j IS the output offset; reads lds[i][pad+sxr..+7],
// masks t<wj (MAX_BIN clamp), 7 maxes, one contiguous 196B store per (n,c).
// Junk dwords beyond col w-1 come from in-bounds loads (finite) or are
// cndmask-discarded; all addresses proven in-row (last col <= 127).

constexpr int kC = 256, kH = 128, kW = 128, kN = 256, kOut = 7;
constexpr int kStr = 68;  // dwords/bin-row: 272B (16B-aligned), 4i bank spread

__device__ __forceinline__ float swz16(float v) {
  // xor-16 lane swap within 32-lane halves: BitMode offset = (16<<10)|31
  return __int_as_float(
      __builtin_amdgcn_ds_swizzle(__float_as_int(v), 0x401f));
}

__global__ __launch_bounds__(256) void roipool_kernel(
    const float* __restrict__ feats,
    const int* __restrict__ rois,
    float* __restrict__ out) {
  __shared__ float lds[4][8 * kStr];  // 8704 B

  const int lane = threadIdx.x & 63;
  const int wid  = __builtin_amdgcn_readfirstlane(threadIdx.x) >> 6;
  const int bid  = blockIdx.x;

  // XCD-affine mapping (perf heuristic): xcd = bid & 7, n-fastest per cg
  const int xcd = bid & 7;
  const int idx = bid >> 3;
  const int n   = idx & (kN - 1);
  const int cg  = ((idx >> 8) << 3) | xcd;
  const int c   = (cg << 2) | wid;

  const int4 roi = ((const int4*)rois)[n];
  const int x = __builtin_amdgcn_readfirstlane(roi.x);
  const int y = __builtin_amdgcn_readfirstlane(roi.y);
  const int w = __builtin_amdgcn_readfirstlane(roi.z);
  const int h = __builtin_amdgcn_readfirstlane(roi.w);

  const int xa   = x & ~3;        // aligned window start
  const int pad  = x & 3;
  const int wa   = pad + w;
  const int qmax = (wa - 1) >> 2; // <= 14

  const int q    = lane & 15;         // col quad
  const int slot = (lane >> 4) & 1;   // row slot within bin
  const int bsel = (lane >> 5) & 1;   // bin within pair

  // wave-uniform per-bin bounds (scalar); bin 7 = dup of 6 (row never read)
  int sy_[8], nr_[8];
#pragma unroll
  for (int i = 0; i < 7; ++i) {
    const int s = y + (i * h) / 7;
    int e = y + ((i + 1) * h + 6) / 7;
    int v = e - s;
    if (v > 8) v = 8;  // MAX_BIN clamp
    sy_[i] = s; nr_[i] = v;
  }
  sy_[7] = sy_[6]; nr_[7] = nr_[6];

  float* __restrict__ wl = lds[wid];
  const float* __restrict__ plane = feats + (size_t)c * (kH * kW);

  if (q <= qmax) {
    const int colo = xa + 4 * q;
#pragma unroll
    for (int k = 0; k < 4; ++k) {
      const int sy0 = sy_[2 * k],     nr0 = nr_[2 * k];
      const int sy1 = sy_[2 * k + 1], nr1 = nr_[2 * k + 1];
      const int nrmax = (nr0 > nr1) ? nr0 : nr1;        // uniform
      const int syv   = bsel ? sy1 : sy0;
      const int nrm1  = (bsel ? nr1 : nr0) - 1;
      float4 m4;
#pragma unroll
      for (int p = 0; p < 4; ++p) {
        if (2 * p < nrmax) {          // wave-uniform skip (p=0 always runs)
          int ridx = 2 * p + slot;
          if (ridx > nrm1) ridx = nrm1;   // dup valid row
          const float4 v =
              *(const float4*)(plane + (syv + ridx) * kW + colo);
          if (p == 0) m4 = v;
          else {
            m4.x = fmaxf(m4.x, v.x); m4.y = fmaxf(m4.y, v.y);
            m4.z = fmaxf(m4.z, v.z); m4.w = fmaxf(m4.w, v.w);
          }
        }
      }
      // combine the two row slots (lane ^ 16 has same q -> same exec state)
      m4.x = fmaxf(m4.x, swz16(m4.x));
      m4.y = fmaxf(m4.y, swz16(m4.y));
      m4.z = fmaxf(m4.z, swz16(m4.z));
      m4.w = fmaxf(m4.w, swz16(m4.w));
      if (!slot) {
        const int bin = 2 * k + bsel;
        *(float4*)&wl[bin * kStr + 4 * q] = m4;
      }
    }
  }

  // drain LDS writes before cross-lane reads (same-wave, no barrier needed)
  asm volatile("s_waitcnt lgkmcnt(0)" ::: "memory");

  // read phase: lane l = i*7 + j -> output offset directly
  const int l49 = (lane < 49) ? lane : 48;
  const int i   = (l49 * 37) >> 8;                 // floor(l49/7)
  const int j   = l49 - i * 7;
  const int jw  = j * w;
  const int sxr = (jw * 9363) >> 16;               // floor(jw/7), exact
  const int exr = ((jw + w + 6) * 9363) >> 16;     // floor(((j+1)w+6)/7)
  int wj = exr - sxr;
  if (wj > 8) wj = 8;                              // MAX_BIN clamp

  const float* __restrict__ rbase = wl + i * kStr + pad + sxr;
  float acc = rbase[0];                            // t=0 always valid
#pragma unroll
  for (int t = 1; t < 8; ++t) {
    const float v = rbase[t];
    acc = fmaxf(acc, (t < wj) ? v : -INFINITY);    // cndmask discards junk
  }

  if (lane < 49)
    out[((size_t)n * kC + c) * 49 + lane] = acc;
}

extern "C" void kernel_launch(void* const* d_in, const int* in_sizes, int n_in,
                              void* d_out, int out_size, void* d_ws, size_t ws_size,
                              hipStream_t stream) {
  const float* feats = (const float*)d_in[0];
  const int*   rois  = (const int*)d_in[1];
  float*       out   = (float*)d_out;
  dim3 grid((kC / 4) * kN);
  dim3 block(256);
  roipool_kernel<<<grid, block, 0, stream>>>(feats, rois, out);
}

// Round 6
// 28.955 us; speedup vs baseline: 5.3509x; 1.3033x over previous
//
#include <hip/hip_runtime.h>
#include <math.h>

// RoI max pooling: feats (1,256,128,128) f32, rois (1,256,4) int32 {x,y,w,h},
// out (N=256, C=256, 7, 7) f32.  One wave per (n, c).
//
// Lane map (load phase): q = lane&7 (column quad), b = lane>>3 (row bin,
// b==7 inactive). Each lane loads ALL rows of its bin for its quad with
// dup-row clamp idx=min(dr, nr-1) -- operand multiset identical to the
// reference's masked dr in range(MAX_BIN=8) -- so rowmax completes
// in-register: NO cross-lane combine, no ds_swizzle. One masked
// ds_write_b128 per quad slot. Two quad slots cover cols [0,64): slot1 =
// 4q, slot2 = 32+4q; slot2 skipped by a WAVE-UNIFORM branch when wa<=32
// (~50% of rois). Rows skipped by uniform dr<nrb (nrb = min(8,(h+12)/7)
// >= every bin's nr). Aligned window [xa, ceil4(x+w)-1] never crosses the
// row end (ceil4(x+w) <= 128), so masked-off lanes use a safe dup addr 0.
//
// Read phase: lane l=i*7+j IS the output offset; reads lds[i][pad+sxr..+7]
// (8 consecutive dwords), masks t<wj (MAX_BIN clamp), 7 maxes, one
// contiguous 196B store. Same-wave DS ordering is in-order -> lgkmcnt(0)
// fence suffices, no barrier (per-wave LDS region).

constexpr int kC = 256, kH = 128, kW = 128, kN = 256, kOut = 7;
constexpr int kStr = 68;  // dwords/bin-row: 16B-aligned, bank base 4*bin

__device__ __forceinline__ float4 fmax4(float4 a, const float4 b) {
  a.x = fmaxf(a.x, b.x); a.y = fmaxf(a.y, b.y);
  a.z = fmaxf(a.z, b.z); a.w = fmaxf(a.w, b.w);
  return a;
}

template <bool Q2>
__device__ __forceinline__ void load_phase(
    const float* __restrict__ prow, const int nrb, const int nrm1,
    const int c1, const int c2, const bool a1, const bool a2,
    const int bin, float* __restrict__ wl) {
  float4 m1 = *(const float4*)(prow + c1);
  float4 m2;
  if (Q2) m2 = *(const float4*)(prow + c2);
#pragma unroll
  for (int dr = 1; dr < 8; ++dr) {
    if (dr < nrb) {                                      // uniform row skip
      const int rofs = ((dr <= nrm1) ? dr : nrm1) << 7;  // dup-row clamp
      m1 = fmax4(m1, *(const float4*)(prow + rofs + c1));
      if (Q2) m2 = fmax4(m2, *(const float4*)(prow + rofs + c2));
    }
  }
  if (a1) *(float4*)(wl + bin * kStr + c1) = m1;
  if (Q2) { if (a2) *(float4*)(wl + bin * kStr + c2) = m2; }
}

__global__ __launch_bounds__(256) void roipool_kernel(
    const float* __restrict__ feats,
    const int* __restrict__ rois,
    float* __restrict__ out) {
  __shared__ float lds[4][7 * kStr];  // 7616 B

  const int lane = threadIdx.x & 63;
  const int wid  = __builtin_amdgcn_readfirstlane(threadIdx.x) >> 6;
  const int bid  = blockIdx.x;

  // XCD-affine mapping (perf heuristic): xcd = bid & 7, n-fastest per cg
  const int xcd = bid & 7;
  const int idx = bid >> 3;
  const int n   = idx & (kN - 1);
  const int cg  = ((idx >> 8) << 3) | xcd;
  const int c   = (cg << 2) | wid;

  const int4 roi = ((const int4*)rois)[n];
  const int x = __builtin_amdgcn_readfirstlane(roi.x);
  const int y = __builtin_amdgcn_readfirstlane(roi.y);
  const int w = __builtin_amdgcn_readfirstlane(roi.z);
  const int h = __builtin_amdgcn_readfirstlane(roi.w);

  const int xa  = x & ~3;
  const int pad = x - xa;
  const int wa  = pad + w;          // <= 59

  const int q  = lane & 7;          // column-quad slot
  const int b  = lane >> 3;         // row-bin slot; b==7 inactive
  const int bc = (b < 7) ? b : 6;   // safe dup bin (writes masked)

  // per-lane bin row bounds (VALU magic-div by 7)
  const int bh   = bc * h;
  const int s_b  = bh / 7;
  int nr         = (bh + h + 6) / 7 - s_b;
  if (nr > 8) nr = 8;               // MAX_BIN clamp
  const int nrm1 = nr - 1;
  const int sy_b = y + s_b;

  int nrb = (h + 12) / 7;           // uniform: nrb >= nr for all bins
  if (nrb > 8) nrb = 8;

  const int c1r = 4 * q;
  const int c2r = 32 + 4 * q;
  const bool a1 = (b < 7) && (c1r < wa);
  const bool a2 = (b < 7) && (c2r < wa);
  const int c1 = a1 ? c1r : 0;      // safe dup address when masked
  const int c2 = a2 ? c2r : 0;

  const float* __restrict__ prow =
      feats + (((unsigned)c << 14) + ((unsigned)sy_b << 7) + (unsigned)xa);

  float* __restrict__ wl = lds[wid];
  if (wa > 32) load_phase<true >(prow, nrb, nrm1, c1, c2, a1, a2, bc, wl);
  else         load_phase<false>(prow, nrb, nrm1, c1, c2, a1, a2, bc, wl);

  // drain LDS writes before cross-lane reads (same-wave, no barrier)
  asm volatile("s_waitcnt lgkmcnt(0)" ::: "memory");

  // read phase: lane l = i*7 + j -> output offset directly
  const int l49 = (lane < 49) ? lane : 48;
  const int i   = (l49 * 37) >> 8;                 // floor(l49/7)
  const int j   = l49 - i * 7;
  const int jw  = j * w;
  const int sxr = (jw * 9363) >> 16;               // floor(jw/7)
  const int exr = ((jw + w + 6) * 9363) >> 16;     // floor(((j+1)w+6)/7)
  int wj = exr - sxr;
  if (wj > 8) wj = 8;                              // MAX_BIN clamp

  const float* __restrict__ rbase = wl + i * kStr + pad + sxr;
  float acc = rbase[0];                            // t=0 always valid
#pragma unroll
  for (int t = 1; t < 8; ++t) {
    const float v = rbase[t];
    acc = fmaxf(acc, (t < wj) ? v : -INFINITY);    // cndmask discards junk
  }

  if (lane < 49)
    out[((size_t)n * kC + c) * 49 + lane] = acc;
}

extern "C" void kernel_launch(void* const* d_in, const int* in_sizes, int n_in,
                              void* d_out, int out_size, void* d_ws, size_t ws_size,
                              hipStream_t stream) {
  const float* feats = (const float*)d_in[0];
  const int*   rois  = (const int*)d_in[1];
  float*       out   = (float*)d_out;
  dim3 grid((kC / 4) * kN);
  dim3 block(256);
  roipool_kernel<<<grid, block, 0, stream>>>(feats, rois, out);
}